// Round 2
// baseline (948.335 us; speedup 1.0000x reference)
//
#include <hip/hip_runtime.h>

#define NF 64
#define NH 32
#define NK 16
#define NNODES 15
#define BLOCK 512
#define NWAVES (BLOCK / 64)

// LDS: subL 960 + permL 2048 + sortL 256 = ~3.3 KB (W2 no longer staged).
// h2 + logits weights are delivered via the SMEM pipe: node made wave-uniform
// (readfirstlane pass loop) -> uniform const-restrict loads -> s_load_dwordx16,
// consumed directly by v_fmac_f32 (SGPR src is free). h1/W1 stays per-lane
// float4 VMEM (L1-hit, proven fine in the 381us baseline) so xs/h1v do NOT
// live across the pass loop -> live set ~80 VGPR, no spill at the 128 cap.

__global__ __attribute__((amdgpu_flat_work_group_size(BLOCK, BLOCK),
                          amdgpu_waves_per_eu(4)))
void tree_mlp_kernel(
    const float* __restrict__ x,
    const float* __restrict__ W1, const float* __restrict__ b1,
    const float* __restrict__ W2, const float* __restrict__ b2,
    const float* __restrict__ W3, const float* __restrict__ b3,
    const float* __restrict__ leaf_best, const int* __restrict__ subset_idx,
    float* __restrict__ out, int N)
{
    __shared__ int      subL[NNODES * NK];     // 960 B
    __shared__ unsigned permL[BLOCK];          // 2048 B
    __shared__ int      sortL[NWAVES * 8];     // 256 B (max nb = 8)

    const int tid  = threadIdx.x;
    const int lane = tid & 63;
    const int wv   = tid >> 6;

    for (int i = tid; i < NNODES * NK; i += BLOCK) subL[i] = subset_idx[i];
    __syncthreads();

    const int s = blockIdx.x * BLOCK + tid;
    int valid = (s < N) ? 1 : 0;
    int id    = valid ? s : 0;      // invalid lanes shadow sample 0 (stay live for ballots)
    int loc = 0, off = 0;

    #pragma unroll 1   // keep level loop rolled (I$)
    for (int level = 0; level < 4; ++level) {
        if (level > 0) {
            // ---- in-block counting sort by loc (nb buckets), ballot-based ----
            const int nb = 1 << level;
            int myrank = 0;
            #pragma unroll 1
            for (int b = 0; b < nb; ++b) {
                const unsigned long long m = __ballot(loc == b);
                if (loc == b)
                    myrank = __popcll(m & ((1ull << lane) - 1ull));
                if (lane == 0)
                    sortL[b * NWAVES + wv] = __popcll(m);
            }
            __syncthreads();
            if (tid == 0) {            // exclusive prefix over (bucket, wave)
                int run = 0;
                for (int i = 0; i < nb * NWAVES; ++i) {
                    const int c = sortL[i];
                    sortL[i] = run;
                    run += c;
                }
            }
            __syncthreads();
            const int slot = sortL[loc * NWAVES + wv] + myrank;
            permL[slot] = ((unsigned)id << 5) | ((unsigned)valid << 4) | (unsigned)loc;
            __syncthreads();
            const unsigned p = permL[tid];
            id    = (int)(p >> 5);
            valid = (int)((p >> 4) & 1u);
            loc   = (int)(p & 15u);
            __syncthreads();           // protect permL/sortL reuse next level
        }

        const int node = off + loc;    // sorted ascending across the wave
        const float* xr = x + (size_t)id * NF;

        // Per-lane subset gather (lane's OWN node), dies after h1.
        float xs[NK];
        const int* si = subL + node * NK;
        #pragma unroll
        for (int k = 0; k < NK; ++k) xs[k] = xr[si[k]];

        // h1 = leaky(W1[node] @ xs + b1) : per-lane float4 VMEM (L1-hit,
        // wave-mostly-uniform addresses) exactly as in the 381us baseline.
        float h1v[NH];
        {
            const float4* w1g = (const float4*)(W1 + node * (NH * NK));
            const float*  b1g = b1 + node * NH;
            #pragma unroll
            for (int j = 0; j < NH; ++j) {
                float acc = b1g[j];
                #pragma unroll
                for (int q = 0; q < NK / 4; ++q) {
                    const float4 t = w1g[j * 4 + q];
                    acc += t.x * xs[q * 4 + 0];
                    acc += t.y * xs[q * 4 + 1];
                    acc += t.z * xs[q * 4 + 2];
                    acc += t.w * xs[q * 4 + 3];
                }
                h1v[j] = (acc >= 0.f) ? acc : 0.01f * acc;
            }
        }

        // h2 + logits with wave-uniform node passes: all weight/bias loads
        // below have uniform addresses -> scalar s_load, SMEM pipe, zero
        // LDS/VMEM pressure. Boundary waves run >=2 passes (avg ~1.27x).
        int bit = 0;
        const int nd0 = __builtin_amdgcn_readfirstlane(node);
        const int nd1 = __builtin_amdgcn_readlane(node, 63);

        #pragma unroll 1
        for (int nd = nd0; nd <= nd1; ++nd) {
            if (!__any(node == nd)) continue;

            const float* w2  = W2 + nd * (NH * NH);
            const float* bb2 = b2 + nd * NH;
            const float* w3  = W3 + nd * (2 * NH);
            const float* bb3 = b3 + nd * 2;

            // h2 = leaky(W2 @ h1 + b2)  (32x32, weights in SGPRs)
            float h2v[NH];
            #pragma unroll 2   // bound in-flight scalar weights (~64 SGPR)
            for (int g = 0; g < NH; ++g) {
                float acc = bb2[g];
                #pragma unroll
                for (int k = 0; k < NH; ++k) acc += w2[g * NH + k] * h1v[k];
                h2v[g] = (acc >= 0.f) ? acc : 0.01f * acc;
            }

            // logits; p0 < 0.5  <=>  l0 < l1 (softmax is monotone)
            float l0 = bb3[0];
            float l1 = bb3[1];
            #pragma unroll
            for (int k = 0; k < NH; ++k) l0 += w3[k] * h2v[k];
            #pragma unroll
            for (int k = 0; k < NH; ++k) l1 += w3[NH + k] * h2v[k];

            if (node == nd) bit = (l0 < l1) ? 1 : 0;
        }

        loc = 2 * loc + bit;
        off = 2 * off + 1;   // node offsets: 0, 1, 3, 7
    }

    if (valid) out[id] = leaf_best[loc];
}

extern "C" void kernel_launch(void* const* d_in, const int* in_sizes, int n_in,
                              void* d_out, int out_size, void* d_ws, size_t ws_size,
                              hipStream_t stream) {
    const float* x         = (const float*)d_in[0];
    const float* W1        = (const float*)d_in[1];
    const float* b1        = (const float*)d_in[2];
    const float* W2        = (const float*)d_in[3];
    const float* b2        = (const float*)d_in[4];
    const float* W3        = (const float*)d_in[5];
    const float* b3        = (const float*)d_in[6];
    const float* leaf_best = (const float*)d_in[7];
    const int*   subset    = (const int*)d_in[8];

    const int N = in_sizes[0] / NF;
    const int grid = (N + BLOCK - 1) / BLOCK;
    tree_mlp_kernel<<<grid, BLOCK, 0, stream>>>(
        x, W1, b1, W2, b2, W3, b3, leaf_best, subset, (float*)d_out, N);
}

// Round 3
// 654.341 us; speedup vs baseline: 1.4493x; 1.4493x over previous
//
#include <hip/hip_runtime.h>

#define NF 64
#define NH 32
#define NK 16
#define NNODES 15
#define BLOCK 512
#define NWAVES (BLOCK / 64)

// LDS: subL 960 + permL 2048 + sortL 256 = ~3.3 KB (W2 not staged).
// h2 + logits weights are delivered via the SMEM pipe: node made wave-uniform
// (readfirstlane pass loop) -> uniform const-restrict loads -> s_load,
// consumed by v_fmac_f32 with SGPR src (free). ALL array loops are FULLY
// unrolled: any runtime index on h1v/h2v demotes the array to scratch
// (round-2 bug: "#pragma unroll 2" on the g loop cost 500 MB of scratch
// traffic). Live set ~85 VGPR < 128 cap at waves_per_eu(4).

__global__ __attribute__((amdgpu_flat_work_group_size(BLOCK, BLOCK),
                          amdgpu_waves_per_eu(4)))
void tree_mlp_kernel(
    const float* __restrict__ x,
    const float* __restrict__ W1, const float* __restrict__ b1,
    const float* __restrict__ W2, const float* __restrict__ b2,
    const float* __restrict__ W3, const float* __restrict__ b3,
    const float* __restrict__ leaf_best, const int* __restrict__ subset_idx,
    float* __restrict__ out, int N)
{
    __shared__ int      subL[NNODES * NK];     // 960 B
    __shared__ unsigned permL[BLOCK];          // 2048 B
    __shared__ int      sortL[NWAVES * 8];     // 256 B (max nb = 8)

    const int tid  = threadIdx.x;
    const int lane = tid & 63;
    const int wv   = tid >> 6;

    for (int i = tid; i < NNODES * NK; i += BLOCK) subL[i] = subset_idx[i];
    __syncthreads();

    const int s = blockIdx.x * BLOCK + tid;
    int valid = (s < N) ? 1 : 0;
    int id    = valid ? s : 0;      // invalid lanes shadow sample 0 (stay live for ballots)
    int loc = 0, off = 0;

    #pragma unroll 1   // keep level loop rolled (I$)
    for (int level = 0; level < 4; ++level) {
        if (level > 0) {
            // ---- in-block counting sort by loc (nb buckets), ballot-based ----
            const int nb = 1 << level;
            int myrank = 0;
            #pragma unroll 1
            for (int b = 0; b < nb; ++b) {
                const unsigned long long m = __ballot(loc == b);
                if (loc == b)
                    myrank = __popcll(m & ((1ull << lane) - 1ull));
                if (lane == 0)
                    sortL[b * NWAVES + wv] = __popcll(m);
            }
            __syncthreads();
            if (tid == 0) {            // exclusive prefix over (bucket, wave)
                int run = 0;
                for (int i = 0; i < nb * NWAVES; ++i) {
                    const int c = sortL[i];
                    sortL[i] = run;
                    run += c;
                }
            }
            __syncthreads();
            const int slot = sortL[loc * NWAVES + wv] + myrank;
            permL[slot] = ((unsigned)id << 5) | ((unsigned)valid << 4) | (unsigned)loc;
            __syncthreads();
            const unsigned p = permL[tid];
            id    = (int)(p >> 5);
            valid = (int)((p >> 4) & 1u);
            loc   = (int)(p & 15u);
            __syncthreads();           // protect permL/sortL reuse next level
        }

        const int node = off + loc;    // sorted ascending across the wave
        const float* xr = x + (size_t)id * NF;

        // Per-lane subset gather (lane's OWN node), dies after h1.
        float xs[NK];
        const int* si = subL + node * NK;
        #pragma unroll
        for (int k = 0; k < NK; ++k) xs[k] = xr[si[k]];

        // h1 = leaky(W1[node] @ xs + b1) : per-lane float4 VMEM (L1-hit,
        // wave-mostly-uniform addresses), as in the 381us baseline.
        float h1v[NH];
        {
            const float4* w1g = (const float4*)(W1 + node * (NH * NK));
            const float*  b1g = b1 + node * NH;
            #pragma unroll
            for (int j = 0; j < NH; ++j) {
                float acc = b1g[j];
                #pragma unroll
                for (int q = 0; q < NK / 4; ++q) {
                    const float4 t = w1g[j * 4 + q];
                    acc += t.x * xs[q * 4 + 0];
                    acc += t.y * xs[q * 4 + 1];
                    acc += t.z * xs[q * 4 + 2];
                    acc += t.w * xs[q * 4 + 3];
                }
                h1v[j] = (acc >= 0.f) ? acc : 0.01f * acc;
            }
        }

        // h2 + logits with wave-uniform node passes: all weight/bias loads
        // below have uniform addresses -> scalar s_load, SMEM pipe, zero
        // LDS/VMEM pressure. Boundary waves run extra passes (avg ~1.34x).
        int bit = 0;
        const int nd0 = __builtin_amdgcn_readfirstlane(node);
        const int nd1 = __builtin_amdgcn_readlane(node, 63);

        #pragma unroll 1
        for (int nd = nd0; nd <= nd1; ++nd) {
            if (!__any(node == nd)) continue;

            const float* w2  = W2 + nd * (NH * NH);
            const float* bb2 = b2 + nd * NH;
            const float* w3  = W3 + nd * (2 * NH);
            const float* bb3 = b3 + nd * 2;

            // h2 = leaky(W2 @ h1 + b2)  (32x32, weights in SGPRs)
            // FULLY unrolled: h2v indices must be compile-time constants.
            float h2v[NH];
            #pragma unroll
            for (int g = 0; g < NH; ++g) {
                float acc = bb2[g];
                #pragma unroll
                for (int k = 0; k < NH; ++k) acc += w2[g * NH + k] * h1v[k];
                h2v[g] = (acc >= 0.f) ? acc : 0.01f * acc;
            }

            // logits; p0 < 0.5  <=>  l0 < l1 (softmax is monotone)
            float l0 = bb3[0];
            float l1 = bb3[1];
            #pragma unroll
            for (int k = 0; k < NH; ++k) l0 += w3[k] * h2v[k];
            #pragma unroll
            for (int k = 0; k < NH; ++k) l1 += w3[NH + k] * h2v[k];

            if (node == nd) bit = (l0 < l1) ? 1 : 0;
        }

        loc = 2 * loc + bit;
        off = 2 * off + 1;   // node offsets: 0, 1, 3, 7
    }

    if (valid) out[id] = leaf_best[loc];
}

extern "C" void kernel_launch(void* const* d_in, const int* in_sizes, int n_in,
                              void* d_out, int out_size, void* d_ws, size_t ws_size,
                              hipStream_t stream) {
    const float* x         = (const float*)d_in[0];
    const float* W1        = (const float*)d_in[1];
    const float* b1        = (const float*)d_in[2];
    const float* W2        = (const float*)d_in[3];
    const float* b2        = (const float*)d_in[4];
    const float* W3        = (const float*)d_in[5];
    const float* b3        = (const float*)d_in[6];
    const float* leaf_best = (const float*)d_in[7];
    const int*   subset    = (const int*)d_in[8];

    const int N = in_sizes[0] / NF;
    const int grid = (N + BLOCK - 1) / BLOCK;
    tree_mlp_kernel<<<grid, BLOCK, 0, stream>>>(
        x, W1, b1, W2, b2, W3, b3, leaf_best, subset, (float*)d_out, N);
}

// Round 4
// 615.552 us; speedup vs baseline: 1.5406x; 1.0630x over previous
//
#include <hip/hip_runtime.h>

#define NF 64
#define NH 32
#define NK 16
#define NNODES 15
#define BLOCK 512
#define NWAVES (BLOCK / 64)

// LDS: subL 960 + permL 2048 + sortL 256 = ~3.3 KB (W2 not staged).
//
// Weight delivery for h2+logits: node is wave-uniform (readfirstlane pass
// loop) -> all W2/b2/W3/b3 addresses uniform -> scalar s_load on the SMEM
// pipe, consumed by v_fmac with SGPR src (free operand).
//
// Register-allocation rules learned in rounds 1-3:
//  * NO register array may be runtime-indexed (r2: h2v[g] -> 500 MB scratch).
//  * NO fully-unrolled 1024-weight scalar block (r3: SGPR window blows past
//    102 -> cascading spill, 170 MB scratch).
// Resolution: roll the g loop (runtime g indexes MEMORY only, uniform) and
// fuse h2 into l0/l1 so h2v never exists; inner k loop fully unrolled so
// h1v keeps static indices. In-flight scalar weights = 1-2 W2 rows.
// FP accumulation order identical to the passing baselines.

__global__ __attribute__((amdgpu_flat_work_group_size(BLOCK, BLOCK),
                          amdgpu_waves_per_eu(2, 4)))
void tree_mlp_kernel(
    const float* __restrict__ x,
    const float* __restrict__ W1, const float* __restrict__ b1,
    const float* __restrict__ W2, const float* __restrict__ b2,
    const float* __restrict__ W3, const float* __restrict__ b3,
    const float* __restrict__ leaf_best, const int* __restrict__ subset_idx,
    float* __restrict__ out, int N)
{
    __shared__ int      subL[NNODES * NK];     // 960 B
    __shared__ unsigned permL[BLOCK];          // 2048 B
    __shared__ int      sortL[NWAVES * 8];     // 256 B (max nb = 8)

    const int tid  = threadIdx.x;
    const int lane = tid & 63;
    const int wv   = tid >> 6;

    for (int i = tid; i < NNODES * NK; i += BLOCK) subL[i] = subset_idx[i];
    __syncthreads();

    const int s = blockIdx.x * BLOCK + tid;
    int valid = (s < N) ? 1 : 0;
    int id    = valid ? s : 0;      // invalid lanes shadow sample 0 (stay live for ballots)
    int loc = 0, off = 0;

    #pragma unroll 1   // keep level loop rolled (I$)
    for (int level = 0; level < 4; ++level) {
        if (level > 0) {
            // ---- in-block counting sort by loc (nb buckets), ballot-based ----
            const int nb = 1 << level;
            int myrank = 0;
            #pragma unroll 1
            for (int b = 0; b < nb; ++b) {
                const unsigned long long m = __ballot(loc == b);
                if (loc == b)
                    myrank = __popcll(m & ((1ull << lane) - 1ull));
                if (lane == 0)
                    sortL[b * NWAVES + wv] = __popcll(m);
            }
            __syncthreads();
            if (tid == 0) {            // exclusive prefix over (bucket, wave)
                int run = 0;
                for (int i = 0; i < nb * NWAVES; ++i) {
                    const int c = sortL[i];
                    sortL[i] = run;
                    run += c;
                }
            }
            __syncthreads();
            const int slot = sortL[loc * NWAVES + wv] + myrank;
            permL[slot] = ((unsigned)id << 5) | ((unsigned)valid << 4) | (unsigned)loc;
            __syncthreads();
            const unsigned p = permL[tid];
            id    = (int)(p >> 5);
            valid = (int)((p >> 4) & 1u);
            loc   = (int)(p & 15u);
            __syncthreads();           // protect permL/sortL reuse next level
        }

        const int node = off + loc;    // sorted ascending across the wave
        const float* xr = x + (size_t)id * NF;

        // Per-lane subset gather (lane's OWN node), dies after h1.
        float xs[NK];
        const int* si = subL + node * NK;
        #pragma unroll
        for (int k = 0; k < NK; ++k) xs[k] = xr[si[k]];

        // h1 = leaky(W1[node] @ xs + b1) : per-lane float4 VMEM (L1-hit,
        // wave-mostly-uniform addresses), exactly as the 381us baseline.
        float h1v[NH];
        {
            const float4* w1g = (const float4*)(W1 + node * (NH * NK));
            const float*  b1g = b1 + node * NH;
            #pragma unroll
            for (int j = 0; j < NH; ++j) {
                float acc = b1g[j];
                #pragma unroll
                for (int q = 0; q < NK / 4; ++q) {
                    const float4 t = w1g[j * 4 + q];
                    acc += t.x * xs[q * 4 + 0];
                    acc += t.y * xs[q * 4 + 1];
                    acc += t.z * xs[q * 4 + 2];
                    acc += t.w * xs[q * 4 + 3];
                }
                h1v[j] = (acc >= 0.f) ? acc : 0.01f * acc;
            }
        }

        // h2 + logits, wave-uniform node passes, h2 fused into l0/l1.
        int bit = 0;
        const int nd0 = __builtin_amdgcn_readfirstlane(node);
        const int nd1 = __builtin_amdgcn_readlane(node, 63);

        #pragma unroll 1
        for (int nd = nd0; nd <= nd1; ++nd) {
            if (!__any(node == nd)) continue;

            const float* w2  = W2 + nd * (NH * NH);
            const float* bb2 = b2 + nd * NH;
            const float* w3  = W3 + nd * (2 * NH);

            float l0 = b3[nd * 2 + 0];
            float l1 = b3[nd * 2 + 1];

            // Rolled over g: runtime g indexes only (uniform) memory, never
            // a register array. unroll 2 = two independent 32-FMA chains.
            #pragma unroll 2
            for (int g = 0; g < NH; ++g) {
                float acc = bb2[g];
                #pragma unroll
                for (int k = 0; k < NH; ++k) acc += w2[g * NH + k] * h1v[k];
                const float h2 = (acc >= 0.f) ? acc : 0.01f * acc;
                l0 += w3[g]      * h2;
                l1 += w3[NH + g] * h2;
            }

            if (node == nd) bit = (l0 < l1) ? 1 : 0;
        }

        loc = 2 * loc + bit;
        off = 2 * off + 1;   // node offsets: 0, 1, 3, 7
    }

    if (valid) out[id] = leaf_best[loc];
}

extern "C" void kernel_launch(void* const* d_in, const int* in_sizes, int n_in,
                              void* d_out, int out_size, void* d_ws, size_t ws_size,
                              hipStream_t stream) {
    const float* x         = (const float*)d_in[0];
    const float* W1        = (const float*)d_in[1];
    const float* b1        = (const float*)d_in[2];
    const float* W2        = (const float*)d_in[3];
    const float* b2        = (const float*)d_in[4];
    const float* W3        = (const float*)d_in[5];
    const float* b3        = (const float*)d_in[6];
    const float* leaf_best = (const float*)d_in[7];
    const int*   subset    = (const int*)d_in[8];

    const int N = in_sizes[0] / NF;
    const int grid = (N + BLOCK - 1) / BLOCK;
    tree_mlp_kernel<<<grid, BLOCK, 0, stream>>>(
        x, W1, b1, W2, b2, W3, b3, leaf_best, subset, (float*)d_out, N);
}

// Round 5
// 487.144 us; speedup vs baseline: 1.9467x; 1.2636x over previous
//
#include <hip/hip_runtime.h>

#define NF 64
#define NH 32
#define NK 16
#define NNODES 15
#define BLOCK 512
#define NWAVES (BLOCK / 64)

// LDS: W2Lv 32768 (current level only, <=8 nodes) + subL 960 + permL 2048
//      + sortL 256 = ~36 KB  (baseline staged all 15 nodes = 65 KB).
//
// Delivery design (evidence r0-r4):
//  * W2 via per-lane LDS reads: after the in-block sort, addresses are
//    wave-uniform -> ds_read_b128 broadcast (free); boundary waves are
//    2-way (free per m136). No readfirstlane pass loop -> no duplicate
//    GEMVs (r4's +38%), no SMEM serialization (r4's stall).
//  * h2 fused into l0/l1 (r4): no h2v array, no runtime-indexed reg array.
//  * W1 per-lane float4 VMEM (L1-hit), as the 381us baseline.
//  * Wave-parallel exclusive scan replaces the serial tid==0 scan.
//  * W2 staging overlaps the sort (between sort barriers, disjoint LDS).

__global__ __attribute__((amdgpu_flat_work_group_size(BLOCK, BLOCK),
                          amdgpu_waves_per_eu(2, 4)))
void tree_mlp_kernel(
    const float* __restrict__ x,
    const float* __restrict__ W1, const float* __restrict__ b1,
    const float* __restrict__ W2, const float* __restrict__ b2,
    const float* __restrict__ W3, const float* __restrict__ b3,
    const float* __restrict__ leaf_best, const int* __restrict__ subset_idx,
    float* __restrict__ out, int N)
{
    __shared__ __align__(16) float W2Lv[8 * 1024];   // 32 KB: this level's nodes
    __shared__ int      subL[NNODES * NK];           // 960 B
    __shared__ unsigned permL[BLOCK];                // 2048 B
    __shared__ int      sortL[64];                   // nb*NWAVES <= 64

    const int tid  = threadIdx.x;
    const int lane = tid & 63;
    const int wv   = tid >> 6;

    // Level-0 staging fused with subL load under the single initial barrier.
    for (int i = tid; i < NNODES * NK; i += BLOCK) subL[i] = subset_idx[i];
    {
        const float4* src = (const float4*)W2;       // node 0
        float4* dst = (float4*)W2Lv;
        for (int i = tid; i < 256; i += BLOCK) dst[i] = src[i];
    }
    __syncthreads();

    const int s = blockIdx.x * BLOCK + tid;
    int valid = (s < N) ? 1 : 0;
    int id    = valid ? s : 0;      // invalid lanes shadow sample 0 (stay live for ballots)
    int loc = 0, off = 0;

    #pragma unroll 1   // keep level loop rolled (I$)
    for (int level = 0; level < 4; ++level) {
        if (level > 0) {
            // ---- in-block counting sort by loc (nb buckets), ballot-based ----
            const int nb = 1 << level;
            int myrank = 0;
            #pragma unroll 1
            for (int b = 0; b < nb; ++b) {
                const unsigned long long m = __ballot(loc == b);
                if (loc == b)
                    myrank = __popcll(m & ((1ull << lane) - 1ull));
                if (lane == 0)
                    sortL[b * NWAVES + wv] = __popcll(m);
            }
            __syncthreads();   // counts visible; prior-level W2Lv reads done

            // Stage this level's W2 slice (overlaps wave-0's scan).
            {
                const int cnt4 = (1 << level) * 256;            // float4s
                const float4* src = (const float4*)(W2 + (size_t)off * 1024);
                float4* dst = (float4*)W2Lv;
                for (int i = tid; i < cnt4; i += BLOCK) dst[i] = src[i];
            }
            // Wave-parallel exclusive scan over (bucket, wave) counts.
            if (wv == 0) {
                const int cnt = nb * NWAVES;                    // 16/32/64
                int v = (lane < cnt) ? sortL[lane] : 0;
                int incl = v;
                #pragma unroll
                for (int d = 1; d < 64; d <<= 1) {
                    int t = __shfl_up(incl, d, 64);
                    if (lane >= d) incl += t;
                }
                if (lane < cnt) sortL[lane] = incl - v;
            }
            __syncthreads();

            const int slot = sortL[loc * NWAVES + wv] + myrank;
            permL[slot] = ((unsigned)id << 5) | ((unsigned)valid << 4) | (unsigned)loc;
            __syncthreads();
            const unsigned p = permL[tid];
            id    = (int)(p >> 5);
            valid = (int)((p >> 4) & 1u);
            loc   = (int)(p & 15u);
            __syncthreads();           // protect permL/sortL reuse next level
        }

        const int node = off + loc;    // wave-uniform after sort (boundaries: 2 nodes)
        const float* xr = x + (size_t)id * NF;

        // Per-lane subset gather; dies after h1.
        float xs[NK];
        const int* si = subL + node * NK;
        #pragma unroll
        for (int k = 0; k < NK; ++k) xs[k] = xr[si[k]];

        // h1 = leaky(W1[node] @ xs + b1) : per-lane float4 VMEM (L1-hit).
        float h1v[NH];
        {
            const float4* w1g = (const float4*)(W1 + node * (NH * NK));
            const float*  b1g = b1 + node * NH;
            #pragma unroll
            for (int j = 0; j < NH; ++j) {
                float acc = b1g[j];
                #pragma unroll
                for (int q = 0; q < NK / 4; ++q) {
                    const float4 t = w1g[j * 4 + q];
                    acc += t.x * xs[q * 4 + 0];
                    acc += t.y * xs[q * 4 + 1];
                    acc += t.z * xs[q * 4 + 2];
                    acc += t.w * xs[q * 4 + 3];
                }
                h1v[j] = (acc >= 0.f) ? acc : 0.01f * acc;
            }
        }

        // h2 fused into logits. W2 row from LDS (broadcast/2-way reads);
        // runtime g indexes MEMORY only, h1v indices static (k fully unrolled).
        const float* w2l = W2Lv + (loc << 10);        // local node = loc
        const float* bb2 = b2 + node * NH;
        const float* w3g = W3 + node * 2 * NH;
        float l0 = b3[node * 2 + 0];
        float l1 = b3[node * 2 + 1];

        #pragma unroll 2
        for (int g = 0; g < NH; ++g) {
            float acc = bb2[g];
            const float4* row = (const float4*)(w2l + g * NH);
            #pragma unroll
            for (int q = 0; q < NH / 4; ++q) {
                const float4 t = row[q];
                acc += t.x * h1v[q * 4 + 0];
                acc += t.y * h1v[q * 4 + 1];
                acc += t.z * h1v[q * 4 + 2];
                acc += t.w * h1v[q * 4 + 3];
            }
            const float h2 = (acc >= 0.f) ? acc : 0.01f * acc;
            l0 += w3g[g]      * h2;
            l1 += w3g[NH + g] * h2;
        }

        const int bit = (l0 < l1) ? 1 : 0;
        loc = 2 * loc + bit;
        off = 2 * off + 1;   // node offsets: 0, 1, 3, 7
    }

    if (valid) out[id] = leaf_best[loc];
}

extern "C" void kernel_launch(void* const* d_in, const int* in_sizes, int n_in,
                              void* d_out, int out_size, void* d_ws, size_t ws_size,
                              hipStream_t stream) {
    const float* x         = (const float*)d_in[0];
    const float* W1        = (const float*)d_in[1];
    const float* b1        = (const float*)d_in[2];
    const float* W2        = (const float*)d_in[3];
    const float* b2        = (const float*)d_in[4];
    const float* W3        = (const float*)d_in[5];
    const float* b3        = (const float*)d_in[6];
    const float* leaf_best = (const float*)d_in[7];
    const int*   subset    = (const int*)d_in[8];

    const int N = in_sizes[0] / NF;
    const int grid = (N + BLOCK - 1) / BLOCK;
    tree_mlp_kernel<<<grid, BLOCK, 0, stream>>>(
        x, W1, b1, W2, b2, W3, b3, leaf_best, subset, (float*)d_out, N);
}